// Round 1
// baseline (13869.308 us; speedup 1.0000x reference)
//
#include <hip/hip_runtime.h>
#include <cstdint>
#include <cstddef>

#define T_STEPS 512
#define BB 64
#define NIN 1024
#define HB 1024
#define NGC 4096
#define GBLK 128
#define HC 8
#define WLD 2056   // padded k-stride (bf16 elems) for LDS W tile: +8 keeps 16B align, breaks bank stride

typedef __attribute__((ext_vector_type(8))) short short8;
typedef __attribute__((ext_vector_type(4))) float float4v;

__device__ __forceinline__ unsigned short f2bf(float f) {
    union { float f; unsigned u; } v; v.f = f;
    unsigned r = v.u + 0x7fffu + ((v.u >> 16) & 1u);   // RNE
    return (unsigned short)(r >> 16);
}

union S8U { short8 v; unsigned short u[8]; };

// ---- one-time X fp32 -> bf16 conversion into workspace ----
__global__ void __launch_bounds__(256) cvt_x_kernel(const float* __restrict__ X,
                                                    unsigned short* __restrict__ Xb) {
    size_t i = ((size_t)blockIdx.x * 256 + threadIdx.x) * 8;
    float4v a = *(const float4v*)(X + i);
    float4v b = *(const float4v*)(X + i + 4);
    S8U o;
    o.u[0] = f2bf(a[0]); o.u[1] = f2bf(a[1]); o.u[2] = f2bf(a[2]); o.u[3] = f2bf(a[3]);
    o.u[4] = f2bf(b[0]); o.u[5] = f2bf(b[1]); o.u[6] = f2bf(b[2]); o.u[7] = f2bf(b[3]);
    *(short8*)(Xb + i) = o.v;
}

// ---- persistent LSTM scan: 128 blocks, full W resident in LDS (bf16) ----
template<int XBF>
__global__ void __launch_bounds__(256, 1)
lstm_scan(const float* __restrict__ X, const unsigned short* __restrict__ Xb,
          const float* __restrict__ W, const float* __restrict__ bias,
          const float* __restrict__ y0, const float* __restrict__ c0,
          const float* __restrict__ imask, float* __restrict__ out,
          unsigned* __restrict__ bar)
{
    extern __shared__ char smem[];
    unsigned short* Wl = (unsigned short*)smem;            // [32][WLD] bf16
    float* zl = (float*)(smem + 32 * WLD * 2);             // [64][33]
    float* cl = zl + 64 * 33;                              // [64][8]
    float* bl = cl + 64 * 8;                               // [32]

    const int g   = blockIdx.x;
    const int tid = threadIdx.x;

    // --- init: W slice -> LDS bf16.  Local col j = gate*8 + c  <->  global col gate*1024 + g*8 + c
    for (int task = tid; task < 2048 * 4; task += 256) {
        int k = task >> 2, gt = task & 3;
        const float* src = W + (size_t)k * NGC + (size_t)gt * HB + (size_t)g * HC;
        #pragma unroll
        for (int c = 0; c < 8; ++c)
            Wl[(gt * 8 + c) * WLD + k] = f2bf(src[c]);
    }
    if (tid < 32) {
        int gt = tid >> 3, c = tid & 7;
        bl[tid] = bias[gt * HB + g * HC + c];
    }
    for (int p = tid; p < 512; p += 256) {
        int r = p >> 3, c = p & 7;
        cl[r * 8 + c] = c0[(size_t)r * HB + g * HC + c];
    }
    __syncthreads();

    const int w = tid >> 6, l = tid & 63;
    const int m16 = l & 15, q = l >> 4;
    const int arow = w * 16 + m16;      // batch row 0..63 this lane supplies
    const int koff = q * 8;             // k offset inside 32-wide k-block
    const unsigned short* wl0 = Wl + (size_t)m16 * WLD + koff;         // cols 0..15
    const unsigned short* wl1 = Wl + (size_t)(16 + m16) * WLD + koff;  // cols 16..31

    float* Yout  = out;
    float* Cout  = out + (size_t)T_STEPS * BB * HB;
    float* cTout = Cout + (size_t)T_STEPS * BB * HB;

    for (int t = 0; t < T_STEPS; ++t) {
        float4v acc0 = {0.f, 0.f, 0.f, 0.f};
        float4v acc1 = {0.f, 0.f, 0.f, 0.f};

        // ---- x_t @ Wx  (k = 0..1023) ----
        if (XBF) {
            const unsigned short* xs = Xb + ((size_t)t * BB + arow) * NIN + koff;
            short8 abuf[8];
            #pragma unroll
            for (int p = 0; p < 8; ++p) abuf[p] = *(const short8*)(xs + p * 32);
            #pragma unroll
            for (int kb = 0; kb < 32; ++kb) {
                short8 a = abuf[kb & 7];
                if (kb + 8 < 32) abuf[kb & 7] = *(const short8*)(xs + (kb + 8) * 32);
                short8 b0 = *(const short8*)(wl0 + kb * 32);
                short8 b1 = *(const short8*)(wl1 + kb * 32);
                acc0 = __builtin_amdgcn_mfma_f32_16x16x32_bf16(a, b0, acc0, 0, 0, 0);
                acc1 = __builtin_amdgcn_mfma_f32_16x16x32_bf16(a, b1, acc1, 0, 0, 0);
            }
        } else {
            const float* xs = X + ((size_t)t * BB + arow) * NIN + koff;
            float4v fb0[4], fb1[4];
            #pragma unroll
            for (int p = 0; p < 4; ++p) {
                fb0[p] = *(const float4v*)(xs + p * 32);
                fb1[p] = *(const float4v*)(xs + p * 32 + 4);
            }
            #pragma unroll
            for (int kb = 0; kb < 32; ++kb) {
                float4v f0 = fb0[kb & 3], f1 = fb1[kb & 3];
                if (kb + 4 < 32) {
                    fb0[kb & 3] = *(const float4v*)(xs + (kb + 4) * 32);
                    fb1[kb & 3] = *(const float4v*)(xs + (kb + 4) * 32 + 4);
                }
                S8U o;
                o.u[0] = f2bf(f0[0]); o.u[1] = f2bf(f0[1]); o.u[2] = f2bf(f0[2]); o.u[3] = f2bf(f0[3]);
                o.u[4] = f2bf(f1[0]); o.u[5] = f2bf(f1[1]); o.u[6] = f2bf(f1[2]); o.u[7] = f2bf(f1[3]);
                short8 b0 = *(const short8*)(wl0 + kb * 32);
                short8 b1 = *(const short8*)(wl1 + kb * 32);
                acc0 = __builtin_amdgcn_mfma_f32_16x16x32_bf16(o.v, b0, acc0, 0, 0, 0);
                acc1 = __builtin_amdgcn_mfma_f32_16x16x32_bf16(o.v, b1, acc1, 0, 0, 0);
            }
        }

        // ---- y_{t-1} @ Wh  (k = 1024..2047), y read fp32 from Y[t-1] (or y0) ----
        {
            const float* ys = (t == 0) ? (y0 + (size_t)arow * HB + koff)
                                       : (Yout + ((size_t)(t - 1) * BB + arow) * HB + koff);
            float4v fb0[4], fb1[4];
            #pragma unroll
            for (int p = 0; p < 4; ++p) {
                fb0[p] = *(const float4v*)(ys + p * 32);
                fb1[p] = *(const float4v*)(ys + p * 32 + 4);
            }
            #pragma unroll
            for (int kb = 0; kb < 32; ++kb) {
                float4v f0 = fb0[kb & 3], f1 = fb1[kb & 3];
                if (kb + 4 < 32) {
                    fb0[kb & 3] = *(const float4v*)(ys + (kb + 4) * 32);
                    fb1[kb & 3] = *(const float4v*)(ys + (kb + 4) * 32 + 4);
                }
                S8U o;
                o.u[0] = f2bf(f0[0]); o.u[1] = f2bf(f0[1]); o.u[2] = f2bf(f0[2]); o.u[3] = f2bf(f0[3]);
                o.u[4] = f2bf(f1[0]); o.u[5] = f2bf(f1[1]); o.u[6] = f2bf(f1[2]); o.u[7] = f2bf(f1[3]);
                short8 b0 = *(const short8*)(wl0 + 1024 + kb * 32);
                short8 b1 = *(const short8*)(wl1 + 1024 + kb * 32);
                acc0 = __builtin_amdgcn_mfma_f32_16x16x32_bf16(o.v, b0, acc0, 0, 0, 0);
                acc1 = __builtin_amdgcn_mfma_f32_16x16x32_bf16(o.v, b1, acc1, 0, 0, 0);
            }
        }

        // ---- z -> LDS (C/D layout: col=lane&15, row=quad*4+reg) ----
        #pragma unroll
        for (int i2 = 0; i2 < 4; ++i2) {
            int r = w * 16 + q * 4 + i2;
            zl[r * 33 + m16]      = acc0[i2];
            zl[r * 33 + 16 + m16] = acc1[i2];
        }
        __syncthreads();

        // ---- gates: 512 (row, h) pairs, 2 per thread ----
        #pragma unroll
        for (int pp = 0; pp < 2; ++pp) {
            int p = tid + pp * 256;
            int r = p >> 3, c = p & 7;
            float z0 = zl[r * 33 + c]      + bl[c];
            float z1 = zl[r * 33 + 8 + c]  + bl[8 + c];
            float z2 = zl[r * 33 + 16 + c] + bl[16 + c];
            float z3 = zl[r * 33 + 24 + c] + bl[24 + c];
            float cprev = cl[r * 8 + c];
            float m = imask[(size_t)t * BB + r];
            float cell = tanhf(z0);
            float ig = 1.f / (1.f + __expf(-z1));
            float fg = 1.f / (1.f + __expf(-z2));
            float og = 1.f / (1.f + __expf(-z3));
            float cn = cell * ig + cprev * fg;
            float yn = tanhf(cn) * og;          // reference: y from pre-mask c
            cn = m * cn + (1.f - m) * cprev;
            yn = m * yn;
            cl[r * 8 + c] = cn;
            size_t oidx = ((size_t)t * BB + r) * HB + (size_t)g * HC + c;
            Yout[oidx] = yn;
            Cout[oidx] = cn;
            if (t == T_STEPS - 1) cTout[(size_t)r * HB + g * HC + c] = cn;
        }

        // ---- grid barrier (monotonic counter, agent-scope fences) ----
        if (t < T_STEPS - 1) {
            __builtin_amdgcn_fence(__ATOMIC_RELEASE, "agent");   // flush y/C stores to coherence point
            __syncthreads();
            if (tid == 0) {
                __hip_atomic_fetch_add(bar, 1u, __ATOMIC_RELAXED, __HIP_MEMORY_SCOPE_AGENT);
                unsigned tgt = (unsigned)(t + 1) * GBLK;
                while (__hip_atomic_load(bar, __ATOMIC_RELAXED, __HIP_MEMORY_SCOPE_AGENT) < tgt)
                    __builtin_amdgcn_s_sleep(1);
            }
            __syncthreads();
            __builtin_amdgcn_fence(__ATOMIC_ACQUIRE, "agent");   // invalidate stale L1/L2 before reading Y[t]
        }
    }
}

extern "C" void kernel_launch(void* const* d_in, const int* in_sizes, int n_in,
                              void* d_out, int out_size, void* d_ws, size_t ws_size,
                              hipStream_t stream) {
    const float* X    = (const float*)d_in[0];
    const float* W    = (const float*)d_in[1];
    const float* bias = (const float*)d_in[2];
    const float* y0   = (const float*)d_in[3];
    const float* c0   = (const float*)d_in[4];
    const float* im   = (const float*)d_in[5];
    float* out = (float*)d_out;

    unsigned* bar = (unsigned*)d_ws;
    unsigned short* Xb = (unsigned short*)((char*)d_ws + 256);
    const size_t xbytes = (size_t)T_STEPS * BB * NIN * sizeof(unsigned short);
    const int use_bf = (ws_size >= 256 + xbytes) ? 1 : 0;
    const int smem_bytes = 32 * WLD * 2 + 64 * 33 * 4 + 64 * 8 * 4 + 32 * 4;  // 142,208 B

    hipMemsetAsync(d_ws, 0, 256, stream);   // zero barrier counter (ws is poisoned each launch)

    if (use_bf) {
        cvt_x_kernel<<<(T_STEPS * BB * NIN) / (256 * 8), 256, 0, stream>>>(X, Xb);
        hipFuncSetAttribute((const void*)lstm_scan<1>,
                            hipFuncAttributeMaxDynamicSharedMemorySize, smem_bytes);
        lstm_scan<1><<<GBLK, 256, smem_bytes, stream>>>(X, Xb, W, bias, y0, c0, im, out, bar);
    } else {
        hipFuncSetAttribute((const void*)lstm_scan<0>,
                            hipFuncAttributeMaxDynamicSharedMemorySize, smem_bytes);
        lstm_scan<0><<<GBLK, 256, smem_bytes, stream>>>(X, Xb, W, bias, y0, c0, im, out, bar);
    }
}